// Round 1
// 274.165 us; speedup vs baseline: 1.1747x; 1.1747x over previous
//
#include <hip/hip_runtime.h>

// BertFusion: out = softmax(H @ V^T) @ V    B=8, L=2048, V=1024, D=1024, fp32.
//
// Fast path (needs 64 MB d_ws):
//   P0: H fp32 -> Hh fp16 (ws, 32 MB)
//   P1: V fp32 -> Vh fp16 (ws, 16 MB) + VTh fp16 transposed (ws, 16 MB)
//   G1: S = Hh @ Vh^T   (fp32 -> d_out)   [256x256 8-phase counted-vmcnt gemm]
//   K2: softmax rows of S -> fp16 P in ws (reuses Hh; dead after G1)
//   G2: O = P @ VTh^T   (fp32 -> d_out)
// Slow path (ws too small): round-2 kernels (proven).
//
// gemm256: 256x256 tile, BK=64, 512 thr (8 waves 2Mx4N), 4 phases/K-tile,
// raw s_barrier (no vmcnt drain), counted s_waitcnt vmcnt(4) at K-tile
// boundaries only (T3+T4), setprio around MFMA clusters (T5), XCD-chunked
// block swizzle (T1). LDS [kgg][256][8] layout: linear for global_load_lds
// AND conflict-free ds_read_b128 (SQ_LDS_BANK_CONFLICT==0 measured on the
// same layout in the 128^2 predecessor).

typedef _Float16 half8_t __attribute__((ext_vector_type(8)));
typedef _Float16 half4_t __attribute__((ext_vector_type(4)));
typedef __fp16   fp16x2  __attribute__((ext_vector_type(2)));
typedef float    f32x4   __attribute__((ext_vector_type(4)));

#define B_ 8
#define L_ 2048
#define V_ 1024
#define D_ 1024

__device__ __forceinline__ half8_t cvt8(f32x4 a, f32x4 b) {
  union { half8_t h; fp16x2 p[4]; } u;
  u.p[0] = __builtin_amdgcn_cvt_pkrtz(a[0], a[1]);
  u.p[1] = __builtin_amdgcn_cvt_pkrtz(a[2], a[3]);
  u.p[2] = __builtin_amdgcn_cvt_pkrtz(b[0], b[1]);
  u.p[3] = __builtin_amdgcn_cvt_pkrtz(b[2], b[3]);
  return u.h;
}
__device__ __forceinline__ half4_t cvt4(f32x4 a) {
  union { half4_t h; fp16x2 p[2]; } u;
  u.p[0] = __builtin_amdgcn_cvt_pkrtz(a[0], a[1]);
  u.p[1] = __builtin_amdgcn_cvt_pkrtz(a[2], a[3]);
  return u.h;
}

__device__ __forceinline__ void gload_lds16(const _Float16* g, _Float16* l) {
  __builtin_amdgcn_global_load_lds(
      (const __attribute__((address_space(1))) unsigned int*)(g),
      (__attribute__((address_space(3))) unsigned int*)(l), 16, 0, 0);
}

// ---------------- P0: H fp32 -> Hh fp16 ----------------
__global__ __launch_bounds__(256) void p0_hconv(const float* __restrict__ H,
                                                _Float16* __restrict__ Hh) {
  const size_t i = ((size_t)blockIdx.x * 256 + threadIdx.x) * 8;  // 8 el/thread
  f32x4 a = *(const f32x4*)(H + i);
  f32x4 b = *(const f32x4*)(H + i + 4);
  *(half8_t*)(Hh + i) = cvt8(a, b);
}

// ---------------- P1: V fp32 -> Vh fp16 + VTh fp16 (transposed) ----------
__global__ __launch_bounds__(256) void p1_vconv(const float* __restrict__ V,
                                                _Float16* __restrict__ Vh,
                                                _Float16* __restrict__ VTh) {
  const int b  = blockIdx.z;
  const int d0 = blockIdx.x * 64;
  const int v0 = blockIdx.y * 64;
  const float* Vb = V + (size_t)b * V_ * D_;
  __shared__ __align__(16) _Float16 Lt[64 * 80];
  const int t   = threadIdx.x;
  const int dc4 = (t & 15) * 4;
  #pragma unroll
  for (int it = 0; it < 4; ++it) {
    const int vr = (t >> 4) + it * 16;
    f32x4 x = *(const f32x4*)(Vb + (size_t)(v0 + vr) * D_ + d0 + dc4);
    half4_t h = cvt4(x);
    *(half4_t*)(Vh + (size_t)b * V_ * D_ + (size_t)(v0 + vr) * D_ + d0 + dc4) = h;
    #pragma unroll
    for (int j = 0; j < 4; ++j) Lt[(dc4 + j) * 80 + vr] = h[j];
  }
  __syncthreads();
  #pragma unroll
  for (int it = 0; it < 2; ++it) {
    const int dr = (t >> 3) + it * 32;
    const int vc = (t & 7) * 8;
    half8_t y = *(const half8_t*)&Lt[dr * 80 + vc];
    *(half8_t*)(VTh + (size_t)b * D_ * V_ + (size_t)(d0 + dr) * V_ + v0 + vc) = y;
  }
}

// ---------------- gemm256: 256^2 8-phase counted-vmcnt fp16 GEMM ----------
// Fixed geometry (both G1 and G2): per batch M=2048, N=1024, K=1024;
// lda=ldb=ldc=1024; batch strides A,C = 2048*1024, B = 1024*1024.
// C[m][n] = sum_k A[m][k]*B[n][k], fp32 out.
#define BARRIER() asm volatile("s_barrier" ::: "memory")

__global__ __launch_bounds__(512, 2) void gemm256(
    const _Float16* __restrict__ A, const _Float16* __restrict__ B,
    float* __restrict__ C) {
  // XCD-chunked bijective swizzle (grid = 256, 256 % 8 == 0):
  // XCD x (= blockIdx %8) gets contiguous wg chunk -> one batch per XCD.
  int lin = blockIdx.x;
  lin = (lin & 7) * 32 + (lin >> 3);
  const int bz = lin >> 5;          // batch
  const int my = (lin >> 2) & 7;    // m-block (consecutive share A panel)
  const int nx = lin & 3;           // n-block
  const int m0 = my * 256, n0 = nx * 256;

  const _Float16* Ap = A + (size_t)bz * (2048 * 1024) + (size_t)m0 * 1024;
  const _Float16* Bp = B + (size_t)bz * (1024 * 1024) + (size_t)n0 * 1024;
  float*          Cp = C + (size_t)bz * (2048 * 1024);

  // [kgg 0..7][row 0..255][8 halves] per buffer; 32 KB per matrix per buffer.
  __shared__ __align__(16) _Float16 As[2][16384];
  __shared__ __align__(16) _Float16 Bs[2][16384];

  const int t    = threadIdx.x;
  const int lane = t & 63;
  const int wid  = t >> 6;
  const int wm   = wid >> 2;   // 0..1  (rows wm*128 .. +127)
  const int wn   = wid & 3;    // 0..3  (cols wn*64 .. +63)
  const int fr   = lane & 15;
  const int fk   = lane >> 4;  // 0..3

  f32x4 acc[8][4];
  {
    f32x4 z = {0.f, 0.f, 0.f, 0.f};
    #pragma unroll
    for (int i = 0; i < 8; ++i)
      #pragma unroll
      for (int j = 0; j < 4; ++j) acc[i][j] = z;
  }

  // stage one half-tile (128 rows x 64 k): 2 x global_load_lds(16B)/thread.
  // cell c = i*512 + t; kgg = c>>7 (const per wave), r = c&127 (consec) ->
  // per-wave LDS dest is 64 consecutive 16B cells (linear, as HW requires).
  #define STG(PTR, LDSB, H, U)                                                 \
    {                                                                          \
      _Pragma("unroll")                                                        \
      for (int i_ = 0; i_ < 2; ++i_) {                                         \
        const int c_ = i_ * 512 + t;                                           \
        const int kg_ = c_ >> 7, r_ = c_ & 127;                                \
        gload_lds16(PTR + (size_t)((H) * 128 + r_) * 1024 + (U) * 64 + kg_ * 8,\
                    &LDSB[(U) & 1][(kg_ * 256 + (H) * 128 + r_) * 8]);         \
      }                                                                        \
    }

  #define LDA_(mt_, ks_) \
    (*(const half8_t*)&As[buf][(((ks_) * 4 + fk) * 256 + wm * 128 + (mt_) * 16 + fr) * 8])
  #define LDB_(nt_, ks_) \
    (*(const half8_t*)&Bs[buf][(((ks_) * 4 + fk) * 256 + wn * 64 + (nt_) * 16 + fr) * 8])

  #define MFMA16(AF, BF, MOFF, NOFF)                                           \
    __builtin_amdgcn_s_setprio(1);                                             \
    _Pragma("unroll")                                                          \
    for (int ks = 0; ks < 2; ++ks)                                             \
      _Pragma("unroll")                                                        \
      for (int nt = 0; nt < 2; ++nt)                                           \
        _Pragma("unroll")                                                      \
        for (int mt = 0; mt < 4; ++mt)                                         \
          acc[(MOFF) + mt][(NOFF) + nt] =                                      \
              __builtin_amdgcn_mfma_f32_16x16x32_f16(                          \
                  AF[mt][ks], BF[nt][ks], acc[(MOFF) + mt][(NOFF) + nt], 0, 0, 0); \
    __builtin_amdgcn_s_setprio(0);

  // Prologue (FIFO: t0 B0,A0,B1,A1; t1 B0,A0 = 12 loads). vmcnt(4) -> all of
  // K-tile 0 landed, t1's B0,A0 (4 loads) still in flight.
  STG(Bp, Bs, 0, 0) STG(Ap, As, 0, 0) STG(Bp, Bs, 1, 0) STG(Ap, As, 1, 0)
  STG(Bp, Bs, 0, 1) STG(Ap, As, 0, 1)
  asm volatile("s_waitcnt vmcnt(4)" ::: "memory");
  BARRIER();

  for (int kt = 0; kt < 16; ++kt) {
    const int buf = kt & 1;
    half8_t a0[4][2], b0[2][2], b1[2][2];

    // ---- P1: read A(m0..3)+B(n0..1); stage (t+1)B1; MFMA quad (m0..3,n0..1)
    #pragma unroll
    for (int ks = 0; ks < 2; ++ks) {
      #pragma unroll
      for (int mt = 0; mt < 4; ++mt) a0[mt][ks] = LDA_(mt, ks);
      #pragma unroll
      for (int nt = 0; nt < 2; ++nt) b0[nt][ks] = LDB_(nt, ks);
    }
    if (kt + 1 < 16) { STG(Bp, Bs, 1, kt + 1) }
    BARRIER();
    MFMA16(a0, b0, 0, 0)
    BARRIER();

    // ---- P2: read B(n2..3); stage (t+1)A1; MFMA quad (m0..3,n2..3)
    #pragma unroll
    for (int ks = 0; ks < 2; ++ks)
      #pragma unroll
      for (int nt = 0; nt < 2; ++nt) b1[nt][ks] = LDB_(2 + nt, ks);
    if (kt + 1 < 16) { STG(Ap, As, 1, kt + 1) }
    BARRIER();
    MFMA16(a0, b1, 0, 2)
    BARRIER();

    // ---- P3: read A(m4..7); stage (t+2)B0 (B0 of cur buf free after P2);
    //          MFMA quad (m4..7,n2..3)
    #pragma unroll
    for (int ks = 0; ks < 2; ++ks)
      #pragma unroll
      for (int mt = 0; mt < 4; ++mt) a0[mt][ks] = LDA_(4 + mt, ks);
    if (kt + 2 < 16) { STG(Bp, Bs, 0, kt + 2) }
    BARRIER();
    MFMA16(a0, b1, 4, 2)
    BARRIER();

    // ---- P4: stage (t+2)A0 (A0 of cur buf free after P3); MFMA (m4..7,n0..1)
    //          boundary wait: counted vmcnt(4) (2 newest half-tiles in flight)
    if (kt + 2 < 16) { STG(Ap, As, 0, kt + 2) }
    BARRIER();
    MFMA16(a0, b0, 4, 0)
    if (kt < 14) {
      asm volatile("s_waitcnt vmcnt(4)" ::: "memory");
    } else if (kt == 14) {
      asm volatile("s_waitcnt vmcnt(0)" ::: "memory");  // tail: t15 fully landed
    }
    BARRIER();
  }
  #undef STG
  #undef LDA_
  #undef LDB_
  #undef MFMA16

  // C/D layout: col = lane&15, row = (lane>>4)*4 + reg   [m89/m91]
  const int rq = (lane >> 4) * 4;
  const int cb = n0 + wn * 64 + (lane & 15);
  const int rb = m0 + wm * 128 + rq;
  #pragma unroll
  for (int mt = 0; mt < 8; ++mt)
    #pragma unroll
    for (int nt = 0; nt < 4; ++nt) {
      #pragma unroll
      for (int r = 0; r < 4; ++r)
        Cp[(size_t)(rb + mt * 16 + r) * 1024 + cb + nt * 16] = acc[mt][nt][r];
    }
}

// ---------------- K2: softmax, one wave per row, no barriers --------------
__global__ __launch_bounds__(256) void k2_softmax(const float* __restrict__ S,
                                                  _Float16* __restrict__ P) {
  const int t    = threadIdx.x;
  const int lane = t & 63;
  const int row  = blockIdx.x * 4 + (t >> 6);
  const float* Sr = S + (size_t)row * V_;

  f32x4 s[4];
  #pragma unroll
  for (int j = 0; j < 4; ++j) s[j] = *(const f32x4*)(Sr + (lane + 64 * j) * 4);

  float m = -1e30f;
  #pragma unroll
  for (int j = 0; j < 4; ++j)
    m = fmaxf(m, fmaxf(fmaxf(s[j][0], s[j][1]), fmaxf(s[j][2], s[j][3])));
  #pragma unroll
  for (int off = 1; off < 64; off <<= 1) m = fmaxf(m, __shfl_xor(m, off, 64));

  float sum = 0.f;
  #pragma unroll
  for (int j = 0; j < 4; ++j) {
    s[j][0] = __expf(s[j][0] - m); s[j][1] = __expf(s[j][1] - m);
    s[j][2] = __expf(s[j][2] - m); s[j][3] = __expf(s[j][3] - m);
    sum += (s[j][0] + s[j][1]) + (s[j][2] + s[j][3]);
  }
  #pragma unroll
  for (int off = 1; off < 64; off <<= 1) sum += __shfl_xor(sum, off, 64);
  const float inv = 1.0f / sum;

  _Float16* Pr = P + (size_t)row * V_;
  #pragma unroll
  for (int j = 0; j < 4; ++j) {
    f32x4 e = {s[j][0] * inv, s[j][1] * inv, s[j][2] * inv, s[j][3] * inv};
    *(half4_t*)(Pr + (lane + 64 * j) * 4) = cvt4(e);
  }
}

// ================= slow fallback (round-2, proven) =================
__global__ __launch_bounds__(256, 2) void k1_slow(
    const float* __restrict__ H, const float* __restrict__ Vv, float* __restrict__ S) {
  const int b  = blockIdx.z;
  const int m0 = blockIdx.y * 128;
  const int n0 = blockIdx.x * 128;
  const float* Hb = H  + (size_t)b * L_ * D_;
  const float* Vb = Vv + (size_t)b * V_ * D_;
  float*       Sb = S  + (size_t)b * L_ * V_;
  __shared__ __align__(16) _Float16 As[2][4096];
  __shared__ __align__(16) _Float16 Bs[2][4096];
  const int t = threadIdx.x, lane = t & 63, wm = (t >> 6) >> 1, wn = (t >> 6) & 1;
  f32x4 acc[4][4];
  { f32x4 z = {0,0,0,0};
    #pragma unroll
    for (int i = 0; i < 4; ++i)
      #pragma unroll
      for (int j = 0; j < 4; ++j) acc[i][j] = z; }
  const int skg = t & 3, sm = t >> 2;
  for (int kt = 0; kt < 32; ++kt) {
    const int kbase = kt * 32 + skg * 8, buf = kt & 1;
    #pragma unroll
    for (int h = 0; h < 2; ++h) {
      const int m = sm + h * 64;
      const float* sa = Hb + (size_t)(m0 + m) * D_ + kbase;
      const float* sb = Vb + (size_t)(n0 + m) * D_ + kbase;
      const int cell = skg * 128 + (m ^ (skg * 2));
      *(half8_t*)&As[buf][cell * 8] = cvt8(*(const f32x4*)sa, *(const f32x4*)(sa + 4));
      *(half8_t*)&Bs[buf][cell * 8] = cvt8(*(const f32x4*)sb, *(const f32x4*)(sb + 4));
    }
    __syncthreads();
    const int fkg = lane >> 4, fr = lane & 15;
    half8_t af[4];
    #pragma unroll
    for (int mt = 0; mt < 4; ++mt)
      af[mt] = *(const half8_t*)&As[buf][(fkg * 128 + ((wm * 64 + mt * 16 + fr) ^ (fkg * 2))) * 8];
    #pragma unroll
    for (int nt = 0; nt < 4; ++nt) {
      half8_t bf = *(const half8_t*)&Bs[buf][(fkg * 128 + ((wn * 64 + nt * 16 + fr) ^ (fkg * 2))) * 8];
      #pragma unroll
      for (int mt = 0; mt < 4; ++mt)
        acc[mt][nt] = __builtin_amdgcn_mfma_f32_16x16x32_f16(af[mt], bf, acc[mt][nt], 0, 0, 0);
    }
  }
  const int rq = (lane >> 4) * 4;
  #pragma unroll
  for (int mt = 0; mt < 4; ++mt)
    #pragma unroll
    for (int nt = 0; nt < 4; ++nt) {
      const int col = n0 + wn * 64 + nt * 16 + (lane & 15);
      const int rb  = m0 + wm * 64 + mt * 16 + rq;
      #pragma unroll
      for (int r = 0; r < 4; ++r) Sb[(size_t)(rb + r) * V_ + col] = acc[mt][nt][r];
    }
}

__global__ __launch_bounds__(256) void k2_slow(float* __restrict__ S) {
  const int row = blockIdx.x;
  float* Sr = S + (size_t)row * V_;
  const int t = threadIdx.x;
  f32x4 s = ((const f32x4*)Sr)[t];
  float m = fmaxf(fmaxf(s[0], s[1]), fmaxf(s[2], s[3]));
  #pragma unroll
  for (int off = 1; off < 64; off <<= 1) m = fmaxf(m, __shfl_xor(m, off, 64));
  __shared__ float redm[4];
  __shared__ float reds[4];
  const int w = t >> 6;
  if ((t & 63) == 0) redm[w] = m;
  __syncthreads();
  m = fmaxf(fmaxf(redm[0], redm[1]), fmaxf(redm[2], redm[3]));
  const float e0 = __expf(s[0] - m), e1 = __expf(s[1] - m);
  const float e2 = __expf(s[2] - m), e3 = __expf(s[3] - m);
  float sum = (e0 + e1) + (e2 + e3);
  #pragma unroll
  for (int off = 1; off < 64; off <<= 1) sum += __shfl_xor(sum, off, 64);
  if ((t & 63) == 0) reds[w] = sum;
  __syncthreads();
  const float inv = 1.0f / ((reds[0] + reds[1]) + (reds[2] + reds[3]));
  half4_t p;
  p[0] = (_Float16)(e0 * inv); p[1] = (_Float16)(e1 * inv);
  p[2] = (_Float16)(e2 * inv); p[3] = (_Float16)(e3 * inv);
  *(half4_t*)((_Float16*)Sr + 4 * t) = p;
}

__global__ __launch_bounds__(512, 2) void k3_slow(
    const float* __restrict__ Vv, float* __restrict__ O) {
  const int b = blockIdx.y, r0 = blockIdx.x * 64;
  const float* Vb = Vv + (size_t)b * V_ * D_;
  float*       Ob = O  + (size_t)b * L_ * D_;
  const _Float16* Pb = (const _Float16*)Ob;
  __shared__ __align__(16) _Float16 Bs[32768];
  const int t = threadIdx.x, lane = t & 63, w = t >> 6;
  f32x4 acc[4][8];
  { f32x4 z = {0,0,0,0};
    #pragma unroll
    for (int i = 0; i < 4; ++i)
      #pragma unroll
      for (int j = 0; j < 8; ++j) acc[i][j] = z; }
  for (int kt = 0; kt < 32; ++kt) {
    const int v0 = kt * 32;
    #pragma unroll
    for (int i = 0; i < 8; ++i) {
      const int c = t + i * 512, kg = c >> 10, d = c & 1023;
      const float* src = Vb + (size_t)(v0 + kg * 8) * D_ + d;
      f32x4 x0, x1;
      x0[0] = src[0*D_]; x0[1] = src[1*D_]; x0[2] = src[2*D_]; x0[3] = src[3*D_];
      x1[0] = src[4*D_]; x1[1] = src[5*D_]; x1[2] = src[6*D_]; x1[3] = src[7*D_];
      *(half8_t*)&Bs[(kg * 1024 + d) * 8] = cvt8(x0, x1);
    }
    __syncthreads();
    const int fkg = lane >> 4, fr = lane & 15;
    half8_t af[4];
    #pragma unroll
    for (int mt = 0; mt < 4; ++mt)
      af[mt] = *(const half8_t*)(Pb + (size_t)(r0 + mt * 16 + fr) * 2048 + v0 + fkg * 8);
    #pragma unroll
    for (int nt = 0; nt < 8; ++nt) {
      half8_t bf = *(const half8_t*)&Bs[(fkg * 1024 + w * 128 + nt * 16 + fr) * 8];
      #pragma unroll
      for (int mt = 0; mt < 4; ++mt)
        acc[mt][nt] = __builtin_amdgcn_mfma_f32_16x16x32_f16(af[mt], bf, acc[mt][nt], 0, 0, 0);
    }
    __syncthreads();
  }
  const int rq = (lane >> 4) * 4;
  #pragma unroll
  for (int mt = 0; mt < 4; ++mt)
    #pragma unroll
    for (int nt = 0; nt < 8; ++nt) {
      const int col = w * 128 + nt * 16 + (lane & 15);
      const int rb  = r0 + mt * 16 + rq;
      #pragma unroll
      for (int r = 0; r < 4; ++r) Ob[(size_t)(rb + r) * D_ + col] = acc[mt][nt][r];
    }
}

extern "C" void kernel_launch(void* const* d_in, const int* in_sizes, int n_in,
                              void* d_out, int out_size, void* d_ws, size_t ws_size,
                              hipStream_t stream) {
  (void)in_sizes; (void)n_in; (void)out_size;
  const float* H  = (const float*)d_in[0];   // (8, 2048, 1024)
  const float* Vv = (const float*)d_in[1];   // (8, 1024, 1024)
  float* O = (float*)d_out;                  // (8, 2048, 1024)

  const size_t need = (size_t)64 * 1024 * 1024;  // Hh/P 32M + Vh 16M + VTh 16M
  if (ws_size >= need && d_ws != nullptr) {
    _Float16* Hh  = (_Float16*)d_ws;            // 32 MB; becomes P after G1
    _Float16* Vh  = Hh + (size_t)B_ * L_ * D_;  // 16 MB
    _Float16* VTh = Vh + (size_t)B_ * V_ * D_;  // 16 MB
    _Float16* P   = Hh;                         // reuse (Hh dead after G1)

    p0_hconv<<<dim3((B_ * L_ * D_) / (256 * 8)), 256, 0, stream>>>(H, Hh);
    p1_vconv<<<dim3(D_ / 64, V_ / 64, B_), 256, 0, stream>>>(Vv, Vh, VTh);
    // S = Hh @ Vh^T  -> d_out
    gemm256<<<dim3(256), 512, 0, stream>>>(Hh, Vh, O);
    // P = softmax(S) -> ws (fp16, dense); 1 wave/row
    k2_softmax<<<dim3(B_ * L_ / 4), 256, 0, stream>>>(O, P);
    // O = P @ VTh^T  -> d_out (A,B both in ws: no aliasing with C)
    gemm256<<<dim3(256), 512, 0, stream>>>(P, VTh, O);
  } else {
    k1_slow<<<dim3(V_ / 128, L_ / 128, B_), 256, 0, stream>>>(H, Vv, O);
    k2_slow<<<dim3(B_ * L_), 256, 0, stream>>>(O);
    k3_slow<<<dim3(L_ / 64, B_), 512, 0, stream>>>(Vv, O);
  }
}

// Round 2
// 255.011 us; speedup vs baseline: 1.2629x; 1.0751x over previous
//
#include <hip/hip_runtime.h>

// BertFusion: out = softmax(H @ V^T) @ V    B=8, L=2048, V=1024, D=1024, fp32.
//
// Fast path (needs 64 MB d_ws):
//   P0: H fp32 -> Hh fp16 (ws, 32 MB)
//   P1: V fp32 -> Vh fp16 (ws, 16 MB) + VTh fp16 transposed (ws, 16 MB)
//   G1: S = Hh @ Vh^T   (fp32 -> d_out)   [256x256 8-phase deep-prefetch gemm]
//   K2: softmax rows of S -> fp16 P in ws (reuses Hh; dead after G1)
//   G2: O = P @ VTh^T   (fp32 -> d_out)
// Slow path (ws too small): round-2 kernels (proven).
//
// gemm256 v2: 256x256 tile, BK=64, 512 thr (8 waves 2Mx4N), 4 phases/K-tile,
// raw s_barrier, DEEP prefetch: all 4 half-tiles of K-tile t+2 staged during
// tile t at the earliest legal phase (LDS-region lifetime: B0 free after
// P1-close, B1 after P2-close, A0/A1 after P3-close), steady-state
// s_waitcnt vmcnt(8) at K-tile boundary only (8-16 loads in flight, >=4
// phases of slack per load). 2 K-tiles per loop iter with literal buffer
// indices. setprio around MFMA clusters (T5), XCD-chunked swizzle (T1).
// LDS [kgg][256][8] cell layout: linear for global_load_lds AND
// conflict-free ds_read_b128 (SQ_LDS_BANK_CONFLICT==0 measured).

typedef _Float16 half8_t __attribute__((ext_vector_type(8)));
typedef _Float16 half4_t __attribute__((ext_vector_type(4)));
typedef __fp16   fp16x2  __attribute__((ext_vector_type(2)));
typedef float    f32x4   __attribute__((ext_vector_type(4)));

#define B_ 8
#define L_ 2048
#define V_ 1024
#define D_ 1024

__device__ __forceinline__ half8_t cvt8(f32x4 a, f32x4 b) {
  union { half8_t h; fp16x2 p[4]; } u;
  u.p[0] = __builtin_amdgcn_cvt_pkrtz(a[0], a[1]);
  u.p[1] = __builtin_amdgcn_cvt_pkrtz(a[2], a[3]);
  u.p[2] = __builtin_amdgcn_cvt_pkrtz(b[0], b[1]);
  u.p[3] = __builtin_amdgcn_cvt_pkrtz(b[2], b[3]);
  return u.h;
}
__device__ __forceinline__ half4_t cvt4(f32x4 a) {
  union { half4_t h; fp16x2 p[2]; } u;
  u.p[0] = __builtin_amdgcn_cvt_pkrtz(a[0], a[1]);
  u.p[1] = __builtin_amdgcn_cvt_pkrtz(a[2], a[3]);
  return u.h;
}

__device__ __forceinline__ void gload_lds16(const _Float16* g, _Float16* l) {
  __builtin_amdgcn_global_load_lds(
      (const __attribute__((address_space(1))) unsigned int*)(g),
      (__attribute__((address_space(3))) unsigned int*)(l), 16, 0, 0);
}

// ---------------- P0: H fp32 -> Hh fp16 ----------------
__global__ __launch_bounds__(256) void p0_hconv(const float* __restrict__ H,
                                                _Float16* __restrict__ Hh) {
  const size_t i = ((size_t)blockIdx.x * 256 + threadIdx.x) * 8;  // 8 el/thread
  f32x4 a = *(const f32x4*)(H + i);
  f32x4 b = *(const f32x4*)(H + i + 4);
  *(half8_t*)(Hh + i) = cvt8(a, b);
}

// ---------------- P1: V fp32 -> Vh fp16 + VTh fp16 (transposed) ----------
__global__ __launch_bounds__(256) void p1_vconv(const float* __restrict__ V,
                                                _Float16* __restrict__ Vh,
                                                _Float16* __restrict__ VTh) {
  const int b  = blockIdx.z;
  const int d0 = blockIdx.x * 64;
  const int v0 = blockIdx.y * 64;
  const float* Vb = V + (size_t)b * V_ * D_;
  __shared__ __align__(16) _Float16 Lt[64 * 80];
  const int t   = threadIdx.x;
  const int dc4 = (t & 15) * 4;
  #pragma unroll
  for (int it = 0; it < 4; ++it) {
    const int vr = (t >> 4) + it * 16;
    f32x4 x = *(const f32x4*)(Vb + (size_t)(v0 + vr) * D_ + d0 + dc4);
    half4_t h = cvt4(x);
    *(half4_t*)(Vh + (size_t)b * V_ * D_ + (size_t)(v0 + vr) * D_ + d0 + dc4) = h;
    #pragma unroll
    for (int j = 0; j < 4; ++j) Lt[(dc4 + j) * 80 + vr] = h[j];
  }
  __syncthreads();
  #pragma unroll
  for (int it = 0; it < 2; ++it) {
    const int dr = (t >> 3) + it * 32;
    const int vc = (t & 7) * 8;
    half8_t y = *(const half8_t*)&Lt[dr * 80 + vc];
    *(half8_t*)(VTh + (size_t)b * D_ * V_ + (size_t)(d0 + dr) * V_ + v0 + vc) = y;
  }
}

// ---------------- gemm256: 256^2 deep-prefetch fp16 GEMM ------------------
// Fixed geometry (both G1 and G2): per batch M=2048, N=1024, K=1024;
// lda=ldb=ldc=1024; batch strides A,C = 2048*1024, B = 1024*1024.
// C[m][n] = sum_k A[m][k] * B[n][k], fp32 out.
#define PH_BAR() asm volatile("s_barrier" ::: "memory")

__global__ __launch_bounds__(512, 2) void gemm256(
    const _Float16* __restrict__ A, const _Float16* __restrict__ B,
    float* __restrict__ C) {
  // XCD-chunked bijective swizzle (grid = 256, 256 % 8 == 0):
  // XCD x (= blockIdx %8) gets contiguous wg chunk -> one batch per XCD.
  int lin = blockIdx.x;
  lin = (lin & 7) * 32 + (lin >> 3);
  const int bz = lin >> 5;          // batch
  const int my = (lin >> 2) & 7;    // m-block (consecutive share A panel)
  const int nx = lin & 3;           // n-block
  const int m0 = my * 256, n0 = nx * 256;

  const _Float16* Ap = A + (size_t)bz * (2048 * 1024) + (size_t)m0 * 1024;
  const _Float16* Bp = B + (size_t)bz * (1024 * 1024) + (size_t)n0 * 1024;
  float*          Cp = C + (size_t)bz * (2048 * 1024);

  // [kgg 0..7][row 0..255][8 halves] per buffer; 32 KB per matrix per buffer.
  __shared__ __align__(16) _Float16 As[2][16384];
  __shared__ __align__(16) _Float16 Bs[2][16384];

  const int t    = threadIdx.x;
  const int lane = t & 63;
  const int wid  = t >> 6;
  const int wm   = wid >> 2;   // 0..1  (rows wm*128 .. +127)
  const int wn   = wid & 3;    // 0..3  (cols wn*64 .. +63)
  const int fr   = lane & 15;
  const int fk   = lane >> 4;  // 0..3

  f32x4 acc[8][4];
  {
    f32x4 z = {0.f, 0.f, 0.f, 0.f};
    #pragma unroll
    for (int i = 0; i < 8; ++i)
      #pragma unroll
      for (int j = 0; j < 4; ++j) acc[i][j] = z;
  }

  // stage one half-tile (128 rows x 64 k): 2 x global_load_lds(16B)/thread.
  // cell c = i*512 + t; kgg = c>>7 (const per wave), r = c&127 (consec) ->
  // per-wave LDS dest is 64 consecutive 16B cells (linear, as HW requires).
  #define STG(PTR, ARR, BUFL, H, KTT)                                          \
    {                                                                          \
      _Pragma("unroll")                                                        \
      for (int i_ = 0; i_ < 2; ++i_) {                                         \
        const int c_ = i_ * 512 + t;                                           \
        const int kg_ = c_ >> 7, r_ = c_ & 127;                                \
        gload_lds16(PTR + (size_t)((H) * 128 + r_) * 1024 + (KTT) * 64 + kg_ * 8, \
                    &ARR[BUFL][(kg_ * 256 + (H) * 128 + r_) * 8]);             \
      }                                                                        \
    }

  #define LDA(BUFL, mt_, ks_) \
    (*(const half8_t*)&As[BUFL][(((ks_) * 4 + fk) * 256 + wm * 128 + (mt_) * 16 + fr) * 8])
  #define LDB(BUFL, nt_, ks_) \
    (*(const half8_t*)&Bs[BUFL][(((ks_) * 4 + fk) * 256 + wn * 64 + (nt_) * 16 + fr) * 8])

  #define MFMA16(AF, BF, MOFF, NOFF)                                           \
    __builtin_amdgcn_s_setprio(1);                                             \
    _Pragma("unroll")                                                          \
    for (int ks = 0; ks < 2; ++ks)                                             \
      _Pragma("unroll")                                                        \
      for (int nt = 0; nt < 2; ++nt)                                           \
        _Pragma("unroll")                                                      \
        for (int mt = 0; mt < 4; ++mt)                                         \
          acc[(MOFF) + mt][(NOFF) + nt] =                                      \
              __builtin_amdgcn_mfma_f32_16x16x32_f16(                          \
                  AF[mt][ks], BF[nt][ks], acc[(MOFF) + mt][(NOFF) + nt], 0, 0, 0); \
    __builtin_amdgcn_s_setprio(0);

  // One K-tile, buffer index BUFL is a literal. Stage slots = earliest legal:
  //   P2: B0(t+2)   (B0 of this buffer last read in P1, closed by P1's bar)
  //   P3: B1(t+2)   (B1 read in P2, closed)
  //   P4: A0,A1(t+2) (A halves read in P1+P3, closed by P3's bar)
  // Boundary: vmcnt(8) keeps t+2's 8 loads in flight, guarantees t+1 landed.
  #define TILE(KT, BUFL)                                                       \
    {                                                                          \
      half8_t a[4][2], b0[2][2], b1[2][2];                                     \
      /* P1: read A(m0..3)+B(n0..1); MFMA (m0..3 x n0..1) */                   \
      _Pragma("unroll")                                                        \
      for (int ks = 0; ks < 2; ++ks) {                                         \
        _Pragma("unroll")                                                      \
        for (int mt = 0; mt < 4; ++mt) a[mt][ks] = LDA(BUFL, mt, ks);          \
        _Pragma("unroll")                                                      \
        for (int nt = 0; nt < 2; ++nt) b0[nt][ks] = LDB(BUFL, nt, ks);         \
      }                                                                        \
      PH_BAR();                                                                \
      MFMA16(a, b0, 0, 0)                                                      \
      PH_BAR();                                                                \
      /* P2: read B(n2..3); stage B0(t+2); MFMA (m0..3 x n2..3) */             \
      _Pragma("unroll")                                                        \
      for (int ks = 0; ks < 2; ++ks)                                           \
        _Pragma("unroll")                                                      \
        for (int nt = 0; nt < 2; ++nt) b1[nt][ks] = LDB(BUFL, 2 + nt, ks);     \
      if ((KT) < 14) { STG(Bp, Bs, BUFL, 0, (KT) + 2) }                        \
      PH_BAR();                                                                \
      MFMA16(a, b1, 0, 2)                                                      \
      PH_BAR();                                                                \
      /* P3: read A(m4..7); stage B1(t+2); MFMA (m4..7 x n2..3) */             \
      _Pragma("unroll")                                                        \
      for (int ks = 0; ks < 2; ++ks)                                           \
        _Pragma("unroll")                                                      \
        for (int mt = 0; mt < 4; ++mt) a[mt][ks] = LDA(BUFL, 4 + mt, ks);      \
      if ((KT) < 14) { STG(Bp, Bs, BUFL, 1, (KT) + 2) }                        \
      PH_BAR();                                                                \
      MFMA16(a, b1, 4, 2)                                                      \
      PH_BAR();                                                                \
      /* P4: stage A0,A1(t+2); MFMA (m4..7 x n0..1); boundary wait */          \
      if ((KT) < 14) { STG(Ap, As, BUFL, 0, (KT) + 2) STG(Ap, As, BUFL, 1, (KT) + 2) } \
      PH_BAR();                                                                \
      MFMA16(a, b0, 4, 0)                                                      \
      if ((KT) <= 13) {                                                        \
        asm volatile("s_waitcnt vmcnt(8)" ::: "memory");                       \
      } else if ((KT) == 14) {                                                 \
        asm volatile("s_waitcnt vmcnt(0)" ::: "memory");                       \
      }                                                                        \
      PH_BAR();                                                                \
    }

  // Prologue: stage K-tiles 0 and 1 (16 loads); vmcnt(8) -> tile 0 landed.
  STG(Bp, Bs, 0, 0, 0) STG(Ap, As, 0, 0, 0) STG(Bp, Bs, 0, 1, 0) STG(Ap, As, 0, 1, 0)
  STG(Bp, Bs, 1, 0, 1) STG(Ap, As, 1, 0, 1) STG(Bp, Bs, 1, 1, 1) STG(Ap, As, 1, 1, 1)
  asm volatile("s_waitcnt vmcnt(8)" ::: "memory");
  PH_BAR();

  #pragma unroll 1
  for (int ktp = 0; ktp < 8; ++ktp) {
    TILE(2 * ktp, 0)
    TILE(2 * ktp + 1, 1)
  }
  #undef TILE
  #undef STG
  #undef LDA
  #undef LDB
  #undef MFMA16

  // C/D layout: col = lane&15, row = (lane>>4)*4 + reg   [m89/m91]
  const int rq = (lane >> 4) * 4;
  const int cb = n0 + wn * 64 + (lane & 15);
  const int rb = m0 + wm * 128 + rq;
  #pragma unroll
  for (int mt = 0; mt < 8; ++mt)
    #pragma unroll
    for (int nt = 0; nt < 4; ++nt) {
      #pragma unroll
      for (int r = 0; r < 4; ++r)
        Cp[(size_t)(rb + mt * 16 + r) * 1024 + cb + nt * 16] = acc[mt][nt][r];
    }
}

// ---------------- K2: softmax, one wave per row, no barriers --------------
__global__ __launch_bounds__(256) void k2_softmax(const float* __restrict__ S,
                                                  _Float16* __restrict__ P) {
  const int t    = threadIdx.x;
  const int lane = t & 63;
  const int row  = blockIdx.x * 4 + (t >> 6);
  const float* Sr = S + (size_t)row * V_;

  f32x4 s[4];
  #pragma unroll
  for (int j = 0; j < 4; ++j) s[j] = *(const f32x4*)(Sr + (lane + 64 * j) * 4);

  float m = -1e30f;
  #pragma unroll
  for (int j = 0; j < 4; ++j)
    m = fmaxf(m, fmaxf(fmaxf(s[j][0], s[j][1]), fmaxf(s[j][2], s[j][3])));
  #pragma unroll
  for (int off = 1; off < 64; off <<= 1) m = fmaxf(m, __shfl_xor(m, off, 64));

  float sum = 0.f;
  #pragma unroll
  for (int j = 0; j < 4; ++j) {
    s[j][0] = __expf(s[j][0] - m); s[j][1] = __expf(s[j][1] - m);
    s[j][2] = __expf(s[j][2] - m); s[j][3] = __expf(s[j][3] - m);
    sum += (s[j][0] + s[j][1]) + (s[j][2] + s[j][3]);
  }
  #pragma unroll
  for (int off = 1; off < 64; off <<= 1) sum += __shfl_xor(sum, off, 64);
  const float inv = 1.0f / sum;

  _Float16* Pr = P + (size_t)row * V_;
  #pragma unroll
  for (int j = 0; j < 4; ++j) {
    f32x4 e = {s[j][0] * inv, s[j][1] * inv, s[j][2] * inv, s[j][3] * inv};
    *(half4_t*)(Pr + (lane + 64 * j) * 4) = cvt4(e);
  }
}

// ================= slow fallback (round-2, proven) =================
__global__ __launch_bounds__(256, 2) void k1_slow(
    const float* __restrict__ H, const float* __restrict__ Vv, float* __restrict__ S) {
  const int b  = blockIdx.z;
  const int m0 = blockIdx.y * 128;
  const int n0 = blockIdx.x * 128;
  const float* Hb = H  + (size_t)b * L_ * D_;
  const float* Vb = Vv + (size_t)b * V_ * D_;
  float*       Sb = S  + (size_t)b * L_ * V_;
  __shared__ __align__(16) _Float16 As[2][4096];
  __shared__ __align__(16) _Float16 Bs[2][4096];
  const int t = threadIdx.x, lane = t & 63, wm = (t >> 6) >> 1, wn = (t >> 6) & 1;
  f32x4 acc[4][4];
  { f32x4 z = {0,0,0,0};
    #pragma unroll
    for (int i = 0; i < 4; ++i)
      #pragma unroll
      for (int j = 0; j < 4; ++j) acc[i][j] = z; }
  const int skg = t & 3, sm = t >> 2;
  for (int kt = 0; kt < 32; ++kt) {
    const int kbase = kt * 32 + skg * 8, buf = kt & 1;
    #pragma unroll
    for (int h = 0; h < 2; ++h) {
      const int m = sm + h * 64;
      const float* sa = Hb + (size_t)(m0 + m) * D_ + kbase;
      const float* sb = Vb + (size_t)(n0 + m) * D_ + kbase;
      const int cell = skg * 128 + (m ^ (skg * 2));
      *(half8_t*)&As[buf][cell * 8] = cvt8(*(const f32x4*)sa, *(const f32x4*)(sa + 4));
      *(half8_t*)&Bs[buf][cell * 8] = cvt8(*(const f32x4*)sb, *(const f32x4*)(sb + 4));
    }
    __syncthreads();
    const int fkg = lane >> 4, fr = lane & 15;
    half8_t af[4];
    #pragma unroll
    for (int mt = 0; mt < 4; ++mt)
      af[mt] = *(const half8_t*)&As[buf][(fkg * 128 + ((wm * 64 + mt * 16 + fr) ^ (fkg * 2))) * 8];
    #pragma unroll
    for (int nt = 0; nt < 4; ++nt) {
      half8_t bf = *(const half8_t*)&Bs[buf][(fkg * 128 + ((wn * 64 + nt * 16 + fr) ^ (fkg * 2))) * 8];
      #pragma unroll
      for (int mt = 0; mt < 4; ++mt)
        acc[mt][nt] = __builtin_amdgcn_mfma_f32_16x16x32_f16(af[mt], bf, acc[mt][nt], 0, 0, 0);
    }
  }
  const int rq = (lane >> 4) * 4;
  #pragma unroll
  for (int mt = 0; mt < 4; ++mt)
    #pragma unroll
    for (int nt = 0; nt < 4; ++nt) {
      const int col = n0 + wn * 64 + nt * 16 + (lane & 15);
      const int rb  = m0 + wm * 64 + mt * 16 + rq;
      #pragma unroll
      for (int r = 0; r < 4; ++r) Sb[(size_t)(rb + r) * V_ + col] = acc[mt][nt][r];
    }
}

__global__ __launch_bounds__(256) void k2_slow(float* __restrict__ S) {
  const int row = blockIdx.x;
  float* Sr = S + (size_t)row * V_;
  const int t = threadIdx.x;
  f32x4 s = ((const f32x4*)Sr)[t];
  float m = fmaxf(fmaxf(s[0], s[1]), fmaxf(s[2], s[3]));
  #pragma unroll
  for (int off = 1; off < 64; off <<= 1) m = fmaxf(m, __shfl_xor(m, off, 64));
  __shared__ float redm[4];
  __shared__ float reds[4];
  const int w = t >> 6;
  if ((t & 63) == 0) redm[w] = m;
  __syncthreads();
  m = fmaxf(fmaxf(redm[0], redm[1]), fmaxf(redm[2], redm[3]));
  const float e0 = __expf(s[0] - m), e1 = __expf(s[1] - m);
  const float e2 = __expf(s[2] - m), e3 = __expf(s[3] - m);
  float sum = (e0 + e1) + (e2 + e3);
  #pragma unroll
  for (int off = 1; off < 64; off <<= 1) sum += __shfl_xor(sum, off, 64);
  if ((t & 63) == 0) reds[w] = sum;
  __syncthreads();
  const float inv = 1.0f / ((reds[0] + reds[1]) + (reds[2] + reds[3]));
  half4_t p;
  p[0] = (_Float16)(e0 * inv); p[1] = (_Float16)(e1 * inv);
  p[2] = (_Float16)(e2 * inv); p[3] = (_Float16)(e3 * inv);
  *(half4_t*)((_Float16*)Sr + 4 * t) = p;
}

__global__ __launch_bounds__(512, 2) void k3_slow(
    const float* __restrict__ Vv, float* __restrict__ O) {
  const int b = blockIdx.y, r0 = blockIdx.x * 64;
  const float* Vb = Vv + (size_t)b * V_ * D_;
  float*       Ob = O  + (size_t)b * L_ * D_;
  const _Float16* Pb = (const _Float16*)Ob;
  __shared__ __align__(16) _Float16 Bs[32768];
  const int t = threadIdx.x, lane = t & 63, w = t >> 6;
  f32x4 acc[4][8];
  { f32x4 z = {0,0,0,0};
    #pragma unroll
    for (int i = 0; i < 4; ++i)
      #pragma unroll
      for (int j = 0; j < 8; ++j) acc[i][j] = z; }
  for (int kt = 0; kt < 32; ++kt) {
    const int v0 = kt * 32;
    #pragma unroll
    for (int i = 0; i < 8; ++i) {
      const int c = t + i * 512, kg = c >> 10, d = c & 1023;
      const float* src = Vb + (size_t)(v0 + kg * 8) * D_ + d;
      f32x4 x0, x1;
      x0[0] = src[0*D_]; x0[1] = src[1*D_]; x0[2] = src[2*D_]; x0[3] = src[3*D_];
      x1[0] = src[4*D_]; x1[1] = src[5*D_]; x1[2] = src[6*D_]; x1[3] = src[7*D_];
      *(half8_t*)&Bs[(kg * 1024 + d) * 8] = cvt8(x0, x1);
    }
    __syncthreads();
    const int fkg = lane >> 4, fr = lane & 15;
    half8_t af[4];
    #pragma unroll
    for (int mt = 0; mt < 4; ++mt)
      af[mt] = *(const half8_t*)(Pb + (size_t)(r0 + mt * 16 + fr) * 2048 + v0 + fkg * 8);
    #pragma unroll
    for (int nt = 0; nt < 8; ++nt) {
      half8_t bf = *(const half8_t*)&Bs[(fkg * 1024 + w * 128 + nt * 16 + fr) * 8];
      #pragma unroll
      for (int mt = 0; mt < 4; ++mt)
        acc[mt][nt] = __builtin_amdgcn_mfma_f32_16x16x32_f16(af[mt], bf, acc[mt][nt], 0, 0, 0);
    }
    __syncthreads();
  }
  const int rq = (lane >> 4) * 4;
  #pragma unroll
  for (int mt = 0; mt < 4; ++mt)
    #pragma unroll
    for (int nt = 0; nt < 8; ++nt) {
      const int col = w * 128 + nt * 16 + (lane & 15);
      const int rb  = r0 + mt * 16 + rq;
      #pragma unroll
      for (int r = 0; r < 4; ++r) Ob[(size_t)(rb + r) * D_ + col] = acc[mt][nt][r];
    }
}

extern "C" void kernel_launch(void* const* d_in, const int* in_sizes, int n_in,
                              void* d_out, int out_size, void* d_ws, size_t ws_size,
                              hipStream_t stream) {
  (void)in_sizes; (void)n_in; (void)out_size;
  const float* H  = (const float*)d_in[0];   // (8, 2048, 1024)
  const float* Vv = (const float*)d_in[1];   // (8, 1024, 1024)
  float* O = (float*)d_out;                  // (8, 2048, 1024)

  const size_t need = (size_t)64 * 1024 * 1024;  // Hh/P 32M + Vh 16M + VTh 16M
  if (ws_size >= need && d_ws != nullptr) {
    _Float16* Hh  = (_Float16*)d_ws;            // 32 MB; becomes P after G1
    _Float16* Vh  = Hh + (size_t)B_ * L_ * D_;  // 16 MB
    _Float16* VTh = Vh + (size_t)B_ * V_ * D_;  // 16 MB
    _Float16* P   = Hh;                         // reuse (Hh dead after G1)

    p0_hconv<<<dim3((B_ * L_ * D_) / (256 * 8)), 256, 0, stream>>>(H, Hh);
    p1_vconv<<<dim3(D_ / 64, V_ / 64, B_), 256, 0, stream>>>(Vv, Vh, VTh);
    // S = Hh @ Vh^T  -> d_out
    gemm256<<<dim3(256), 512, 0, stream>>>(Hh, Vh, O);
    // P = softmax(S) -> ws (fp16, dense); 1 wave/row
    k2_softmax<<<dim3(B_ * L_ / 4), 256, 0, stream>>>(O, P);
    // O = P @ VTh^T  -> d_out (A,B both in ws: no aliasing with C)
    gemm256<<<dim3(256), 512, 0, stream>>>(P, VTh, O);
  } else {
    k1_slow<<<dim3(V_ / 128, L_ / 128, B_), 256, 0, stream>>>(H, Vv, O);
    k2_slow<<<dim3(B_ * L_), 256, 0, stream>>>(O);
    k3_slow<<<dim3(L_ / 64, B_), 512, 0, stream>>>(Vv, O);
  }
}